// Round 6
// baseline (4393.423 us; speedup 1.0000x reference)
//
#include <hip/hip_runtime.h>

#define N_NODES 50000
#define N_EDGES 800000
#define IN_CH 64
#define HIDDEN 128
#define OUT_CH 64
#define NB 4   // nodes per MLP block

typedef unsigned short ushort_t;

__device__ __forceinline__ float bits2f(unsigned int u16) {
    union { unsigned int i; float f; } v;
    v.i = (u16 & 0xFFFFu) << 16;
    return v.f;
}

__device__ __forceinline__ ushort_t f2bits(float f) {
    union { float f; unsigned int i; } v;
    v.f = f;
    unsigned int x = v.i;
    if ((x & 0x7F800000u) == 0x7F800000u) return (ushort_t)(x >> 16); // inf/nan
    unsigned int r = (x + 0x7FFFu + ((x >> 16) & 1u)) >> 16;          // RNE
    return (ushort_t)r;
}

// ---- scatter-add layer 1: gather x[src] (f32, 64ch) -> atomicAdd agg1 (f32)
// 8 threads/edge, 8 channels each
__global__ __launch_bounds__(256) void scatter1(const float* __restrict__ x,
                                                const int* __restrict__ ei,
                                                float* __restrict__ agg) {
    unsigned int t = blockIdx.x * 256u + threadIdx.x;
    int e = (int)(t >> 3);
    if (e >= N_EDGES) return;
    int cg = ((int)t & 7) << 3;
    int src = ei[e];
    int dst = ei[N_EDGES + e];
    const float4 a = *reinterpret_cast<const float4*>(x + (size_t)src * IN_CH + cg);
    const float4 b = *reinterpret_cast<const float4*>(x + (size_t)src * IN_CH + cg + 4);
    float* ap = agg + (size_t)dst * IN_CH + cg;
    atomicAdd(ap + 0, a.x);
    atomicAdd(ap + 1, a.y);
    atomicAdd(ap + 2, a.z);
    atomicAdd(ap + 3, a.w);
    atomicAdd(ap + 4, b.x);
    atomicAdd(ap + 5, b.y);
    atomicAdd(ap + 6, b.z);
    atomicAdd(ap + 7, b.w);
}

// ---- scatter-add layer 2: gather h1[src] (bf16, 128ch) -> atomicAdd agg2 (f32)
// 16 threads/edge, 8 channels each
__global__ __launch_bounds__(256) void scatter2(const ushort_t* __restrict__ h1,
                                                const int* __restrict__ ei,
                                                float* __restrict__ agg) {
    unsigned int t = blockIdx.x * 256u + threadIdx.x;
    int e = (int)(t >> 4);
    if (e >= N_EDGES) return;
    int cg = ((int)t & 15) << 3;
    int src = ei[e];
    int dst = ei[N_EDGES + e];
    const uint4 v = *reinterpret_cast<const uint4*>(h1 + (size_t)src * HIDDEN + cg);
    float* ap = agg + (size_t)dst * HIDDEN + cg;
    atomicAdd(ap + 0, bits2f(v.x));
    atomicAdd(ap + 1, bits2f(v.x >> 16));
    atomicAdd(ap + 2, bits2f(v.y));
    atomicAdd(ap + 3, bits2f(v.y >> 16));
    atomicAdd(ap + 4, bits2f(v.z));
    atomicAdd(ap + 5, bits2f(v.z >> 16));
    atomicAdd(ap + 6, bits2f(v.w));
    atomicAdd(ap + 7, bits2f(v.w >> 16));
}

// ---- fused GIN layer-1 MLP, NB nodes/block:
//      h = (1+eps)*x + agg1;  h1 = relu( relu(h@W1+b1) @ W2 + b2 )  -> bf16
__global__ __launch_bounds__(128) void mlp1(const float* __restrict__ x,
                                            const float* __restrict__ agg1,
                                            const float* __restrict__ W1,
                                            const float* __restrict__ b1,
                                            const float* __restrict__ W2,
                                            const float* __restrict__ b2,
                                            const float* __restrict__ eps1,
                                            ushort_t* __restrict__ h1) {
    __shared__ float hs[NB][IN_CH];
    __shared__ float ts[NB][HIDDEN];
    int n0 = blockIdx.x * NB;
    int j = threadIdx.x;
    float se = 1.0f + eps1[0];
    for (int i = j; i < NB * IN_CH; i += 128) {
        int nn = i >> 6, kk = i & 63;
        size_t idx = (size_t)(n0 + nn) * IN_CH + kk;
        hs[nn][kk] = se * x[idx] + agg1[idx];
    }
    __syncthreads();
    float acc[NB];
#pragma unroll
    for (int q = 0; q < NB; q++) acc[q] = b1[j];
#pragma unroll 8
    for (int k = 0; k < IN_CH; k++) {
        float w = W1[(size_t)k * HIDDEN + j];
#pragma unroll
        for (int q = 0; q < NB; q++) acc[q] = fmaf(hs[q][k], w, acc[q]);
    }
#pragma unroll
    for (int q = 0; q < NB; q++) ts[q][j] = fmaxf(acc[q], 0.0f);
    __syncthreads();
    float acc2[NB];
#pragma unroll
    for (int q = 0; q < NB; q++) acc2[q] = b2[j];
#pragma unroll 8
    for (int k = 0; k < HIDDEN; k++) {
        float w = W2[(size_t)k * HIDDEN + j];
#pragma unroll
        for (int q = 0; q < NB; q++) acc2[q] = fmaf(ts[q][k], w, acc2[q]);
    }
#pragma unroll
    for (int q = 0; q < NB; q++)
        h1[(size_t)(n0 + q) * HIDDEN + j] = f2bits(fmaxf(acc2[q], 0.0f));
}

// ---- fused GIN layer-2 MLP, NB nodes/block:
//      h = (1+eps)*h1 + agg2;  out = relu(h@W3+b3) @ W4 + b4  -> f32 (no outer relu)
__global__ __launch_bounds__(128) void mlp2(const ushort_t* __restrict__ h1,
                                            const float* __restrict__ agg2,
                                            const float* __restrict__ W3,
                                            const float* __restrict__ b3,
                                            const float* __restrict__ W4,
                                            const float* __restrict__ b4,
                                            const float* __restrict__ eps2,
                                            float* __restrict__ out) {
    __shared__ float hs[NB][HIDDEN];
    __shared__ float ts[NB][HIDDEN];
    int n0 = blockIdx.x * NB;
    int j = threadIdx.x;
    float se = 1.0f + eps2[0];
    for (int i = j; i < NB * HIDDEN; i += 128) {
        int nn = i >> 7, kk = i & 127;
        size_t idx = (size_t)(n0 + nn) * HIDDEN + kk;
        hs[nn][kk] = se * bits2f(h1[idx]) + agg2[idx];
    }
    __syncthreads();
    float acc[NB];
#pragma unroll
    for (int q = 0; q < NB; q++) acc[q] = b3[j];
#pragma unroll 8
    for (int k = 0; k < HIDDEN; k++) {
        float w = W3[(size_t)k * HIDDEN + j];
#pragma unroll
        for (int q = 0; q < NB; q++) acc[q] = fmaf(hs[q][k], w, acc[q]);
    }
#pragma unroll
    for (int q = 0; q < NB; q++) ts[q][j] = fmaxf(acc[q], 0.0f);
    __syncthreads();
    if (j < OUT_CH) {
        float acc2[NB];
#pragma unroll
        for (int q = 0; q < NB; q++) acc2[q] = b4[j];
#pragma unroll 8
        for (int k = 0; k < HIDDEN; k++) {
            float w = W4[(size_t)k * OUT_CH + j];
#pragma unroll
            for (int q = 0; q < NB; q++) acc2[q] = fmaf(ts[q][k], w, acc2[q]);
        }
#pragma unroll
        for (int q = 0; q < NB; q++)
            out[(size_t)(n0 + q) * OUT_CH + j] = acc2[q];
    }
}

extern "C" void kernel_launch(void* const* d_in, const int* in_sizes, int n_in,
                              void* d_out, int out_size, void* d_ws, size_t ws_size,
                              hipStream_t stream) {
    const float* x    = (const float*)d_in[0];
    const int*   ei   = (const int*)d_in[1];
    const float* W1   = (const float*)d_in[2];
    const float* b1   = (const float*)d_in[3];
    const float* W2   = (const float*)d_in[4];
    const float* b2   = (const float*)d_in[5];
    const float* eps1 = (const float*)d_in[6];
    const float* W3   = (const float*)d_in[7];
    const float* b3   = (const float*)d_in[8];
    const float* W4   = (const float*)d_in[9];
    const float* b4   = (const float*)d_in[10];
    const float* eps2 = (const float*)d_in[11];
    float* out = (float*)d_out;

    // Workspace (38.4 MB, proven in-bounds in R4):
    //   ws[0 .. 6.4M floats)    agg2 region (agg1 overlays its first 3.2M floats)
    //   ws[6.4M floats .. )     h1 as bf16 (6.4M ushorts = 12.8 MB)
    float* ws   = (float*)d_ws;
    float* agg1 = ws;
    float* agg2 = ws;
    ushort_t* h1 = (ushort_t*)(ws + (size_t)N_NODES * HIDDEN);

    // ---- layer 1 ----
    hipMemsetAsync(agg1, 0, (size_t)N_NODES * IN_CH * sizeof(float), stream);
    scatter1<<<(N_EDGES * 8 + 255) / 256, 256, 0, stream>>>(x, ei, agg1);
    mlp1<<<N_NODES / NB, 128, 0, stream>>>(x, agg1, W1, b1, W2, b2, eps1, h1);

    // ---- layer 2 ---- (agg2 overlays agg1; zero only after mlp1 is done)
    hipMemsetAsync(agg2, 0, (size_t)N_NODES * HIDDEN * sizeof(float), stream);
    scatter2<<<(N_EDGES * 16 + 255) / 256, 256, 0, stream>>>(h1, ei, agg2);
    mlp2<<<N_NODES / NB, 128, 0, stream>>>(h1, agg2, W3, b3, W4, b4, eps2, out);
}

// Round 7
// 501.406 us; speedup vs baseline: 8.7622x; 8.7622x over previous
//
#include <hip/hip_runtime.h>

#define N_NODES 50000
#define N_EDGES 800000
#define IN_CH 64
#define HIDDEN 128
#define OUT_CH 64
#define NB 4   // nodes per MLP block

typedef unsigned short ushort_t;
typedef unsigned int uint_t;

__device__ __forceinline__ float bits2f(unsigned int u16) {
    union { unsigned int i; float f; } v;
    v.i = (u16 & 0xFFFFu) << 16;
    return v.f;
}

__device__ __forceinline__ ushort_t f2bits(float f) {
    union { float f; unsigned int i; } v;
    v.f = f;
    unsigned int x = v.i;
    if ((x & 0x7F800000u) == 0x7F800000u) return (ushort_t)(x >> 16); // inf/nan
    unsigned int r = (x + 0x7FFFu + ((x >> 16) & 1u)) >> 16;          // RNE
    return (ushort_t)r;
}

// ======================= CSR build (by dst) =======================
// deg/cursor share one array: hist fills it with degrees, scan converts it
// in place to row-start cursors, fill bumps the cursors.

__global__ __launch_bounds__(256) void hist_k(const int* __restrict__ ei,
                                              int* __restrict__ deg) {
    int e = blockIdx.x * 256 + threadIdx.x;
    if (e >= N_EDGES) return;
    atomicAdd(&deg[ei[N_EDGES + e]], 1);
}

// single-block exclusive scan over N_NODES degrees; writes row[] and cursor[]
__global__ __launch_bounds__(1024) void scan_k(int* deg_cursor, int* row) {
    __shared__ int ssum[1024];
    const int CH = (N_NODES + 1023) / 1024;  // 49
    int t = threadIdx.x;
    int lo = t * CH;
    int hi = lo + CH; if (hi > N_NODES) hi = N_NODES;
    if (lo > N_NODES) lo = N_NODES;
    int s = 0;
    for (int i = lo; i < hi; i++) s += deg_cursor[i];
    ssum[t] = s;
    __syncthreads();
    for (int off = 1; off < 1024; off <<= 1) {
        int v = ssum[t];
        int u = (t >= off) ? ssum[t - off] : 0;
        __syncthreads();
        ssum[t] = v + u;
        __syncthreads();
    }
    int run = (t == 0) ? 0 : ssum[t - 1];
    for (int i = lo; i < hi; i++) {
        int d = deg_cursor[i];
        row[i] = run;
        deg_cursor[i] = run;   // cursor for fill
        run += d;
    }
    if (t == 1023) row[N_NODES] = run;   // == N_EDGES
}

__global__ __launch_bounds__(256) void fill_k(const int* __restrict__ ei,
                                              int* __restrict__ cursor,
                                              int* __restrict__ bucket) {
    int e = blockIdx.x * 256 + threadIdx.x;
    if (e >= N_EDGES) return;
    int src = ei[e];
    int dst = ei[N_EDGES + e];
    int pos = atomicAdd(&cursor[dst], 1);
    bucket[pos] = src;
}

// ======================= gather aggregations =======================
// gather1: one wave per node, lane = channel (64ch f32).
// h[n][c] = (1+eps1)*x[n][c] + sum_{s in N(n)} x[s][c]
__global__ __launch_bounds__(256) void gather1(const float* __restrict__ x,
                                               const int* __restrict__ row,
                                               const int* __restrict__ bucket,
                                               const float* __restrict__ eps1,
                                               float* __restrict__ h) {
    int wid = threadIdx.x >> 6;
    int lane = threadIdx.x & 63;
    int n = blockIdx.x * 4 + wid;
    float acc0 = (1.0f + eps1[0]) * x[(size_t)n * IN_CH + lane];
    float acc1 = 0.0f;
    int lo = row[n], hi = row[n + 1];
    int i = lo;
    for (; i + 1 < hi; i += 2) {
        int s0 = bucket[i], s1 = bucket[i + 1];
        acc0 += x[(size_t)s0 * IN_CH + lane];
        acc1 += x[(size_t)s1 * IN_CH + lane];
    }
    if (i < hi) acc0 += x[(size_t)bucket[i] * IN_CH + lane];
    h[(size_t)n * IN_CH + lane] = acc0 + acc1;
}

// gather2: one wave per node, lane handles 2 bf16 channels via one uint load.
// hbuf[n][c] = (1+eps2)*h1[n][c] + sum h1[s][c]
__global__ __launch_bounds__(256) void gather2(const ushort_t* __restrict__ h1,
                                               const int* __restrict__ row,
                                               const int* __restrict__ bucket,
                                               const float* __restrict__ eps2,
                                               float* __restrict__ hbuf) {
    int wid = threadIdx.x >> 6;
    int lane = threadIdx.x & 63;
    int n = blockIdx.x * 4 + wid;
    const uint_t* h1u = (const uint_t*)h1;
    uint_t v = h1u[(size_t)n * 64 + lane];
    float se = 1.0f + eps2[0];
    float a0 = se * bits2f(v), a1 = se * bits2f(v >> 16);
    float b0 = 0.0f, b1 = 0.0f;
    int lo = row[n], hi = row[n + 1];
    int i = lo;
    for (; i + 1 < hi; i += 2) {
        int s0 = bucket[i], s1 = bucket[i + 1];
        uint_t u0 = h1u[(size_t)s0 * 64 + lane];
        uint_t u1 = h1u[(size_t)s1 * 64 + lane];
        a0 += bits2f(u0); a1 += bits2f(u0 >> 16);
        b0 += bits2f(u1); b1 += bits2f(u1 >> 16);
    }
    if (i < hi) {
        uint_t u = h1u[(size_t)bucket[i] * 64 + lane];
        a0 += bits2f(u); a1 += bits2f(u >> 16);
    }
    float2* outp = (float2*)(hbuf + (size_t)n * HIDDEN + 2 * lane);
    *outp = make_float2(a0 + b0, a1 + b1);
}

// ======================= fused MLPs =======================
// mlp1: h1 = relu( relu(h@W1+b1) @ W2 + b2 )  -> bf16
__global__ __launch_bounds__(128) void mlp1(const float* __restrict__ h,
                                            const float* __restrict__ W1,
                                            const float* __restrict__ b1,
                                            const float* __restrict__ W2,
                                            const float* __restrict__ b2,
                                            ushort_t* __restrict__ h1) {
    __shared__ float hs[NB][IN_CH];
    __shared__ float ts[NB][HIDDEN];
    int n0 = blockIdx.x * NB;
    int j = threadIdx.x;
    for (int i = j; i < NB * IN_CH; i += 128) {
        int nn = i >> 6, kk = i & 63;
        hs[nn][kk] = h[(size_t)(n0 + nn) * IN_CH + kk];
    }
    __syncthreads();
    float acc[NB];
#pragma unroll
    for (int q = 0; q < NB; q++) acc[q] = b1[j];
#pragma unroll 8
    for (int k = 0; k < IN_CH; k++) {
        float w = W1[(size_t)k * HIDDEN + j];
#pragma unroll
        for (int q = 0; q < NB; q++) acc[q] = fmaf(hs[q][k], w, acc[q]);
    }
#pragma unroll
    for (int q = 0; q < NB; q++) ts[q][j] = fmaxf(acc[q], 0.0f);
    __syncthreads();
    float acc2[NB];
#pragma unroll
    for (int q = 0; q < NB; q++) acc2[q] = b2[j];
#pragma unroll 8
    for (int k = 0; k < HIDDEN; k++) {
        float w = W2[(size_t)k * HIDDEN + j];
#pragma unroll
        for (int q = 0; q < NB; q++) acc2[q] = fmaf(ts[q][k], w, acc2[q]);
    }
#pragma unroll
    for (int q = 0; q < NB; q++)
        h1[(size_t)(n0 + q) * HIDDEN + j] = f2bits(fmaxf(acc2[q], 0.0f));
}

// mlp2: out = relu(h@W3+b3) @ W4 + b4  -> f32
__global__ __launch_bounds__(128) void mlp2(const float* __restrict__ h,
                                            const float* __restrict__ W3,
                                            const float* __restrict__ b3,
                                            const float* __restrict__ W4,
                                            const float* __restrict__ b4,
                                            float* __restrict__ out) {
    __shared__ float hs[NB][HIDDEN];
    __shared__ float ts[NB][HIDDEN];
    int n0 = blockIdx.x * NB;
    int j = threadIdx.x;
    for (int i = j; i < NB * HIDDEN; i += 128) {
        int nn = i >> 7, kk = i & 127;
        hs[nn][kk] = h[(size_t)(n0 + nn) * HIDDEN + kk];
    }
    __syncthreads();
    float acc[NB];
#pragma unroll
    for (int q = 0; q < NB; q++) acc[q] = b3[j];
#pragma unroll 8
    for (int k = 0; k < HIDDEN; k++) {
        float w = W3[(size_t)k * HIDDEN + j];
#pragma unroll
        for (int q = 0; q < NB; q++) acc[q] = fmaf(hs[q][k], w, acc[q]);
    }
#pragma unroll
    for (int q = 0; q < NB; q++) ts[q][j] = fmaxf(acc[q], 0.0f);
    __syncthreads();
    if (j < OUT_CH) {
        float acc2[NB];
#pragma unroll
        for (int q = 0; q < NB; q++) acc2[q] = b4[j];
#pragma unroll 8
        for (int k = 0; k < HIDDEN; k++) {
            float w = W4[(size_t)k * OUT_CH + j];
#pragma unroll
            for (int q = 0; q < NB; q++) acc2[q] = fmaf(ts[q][k], w, acc2[q]);
        }
#pragma unroll
        for (int q = 0; q < NB; q++)
            out[(size_t)(n0 + q) * OUT_CH + j] = acc2[q];
    }
}

extern "C" void kernel_launch(void* const* d_in, const int* in_sizes, int n_in,
                              void* d_out, int out_size, void* d_ws, size_t ws_size,
                              hipStream_t stream) {
    const float* x    = (const float*)d_in[0];
    const int*   ei   = (const int*)d_in[1];
    const float* W1   = (const float*)d_in[2];
    const float* b1   = (const float*)d_in[3];
    const float* W2   = (const float*)d_in[4];
    const float* b2   = (const float*)d_in[5];
    const float* eps1 = (const float*)d_in[6];
    const float* W3   = (const float*)d_in[7];
    const float* b3   = (const float*)d_in[8];
    const float* W4   = (const float*)d_in[9];
    const float* b4   = (const float*)d_in[10];
    const float* eps2 = (const float*)d_in[11];
    float* out = (float*)d_out;

    // Workspace layout (~42 MB):
    //   [0 .. 6.4M floats)        agg2/h-buf region (agg1/h overlays first 3.2M)
    //   [6.4M .. 9.6M floats)     h1 as bf16 (6.4M ushorts)
    //   [9.6M .. 10.4M floats)    bucket (800K ints)
    //   [10.4M .. +50001 ints)    row_start
    //   then                      cursor/deg (50000 ints)
    float* ws   = (float*)d_ws;
    float* agg1 = ws;
    float* agg2 = ws;
    ushort_t* h1 = (ushort_t*)(ws + (size_t)N_NODES * HIDDEN);
    int* bucket  = (int*)(ws + (size_t)N_NODES * HIDDEN + (size_t)N_NODES * HIDDEN / 2);
    int* row     = bucket + N_EDGES;
    int* cursor  = row + N_NODES + 4;

    // ---- CSR build (shared by both layers) ----
    hipMemsetAsync(cursor, 0, N_NODES * sizeof(int), stream);
    hist_k<<<(N_EDGES + 255) / 256, 256, 0, stream>>>(ei, cursor);
    scan_k<<<1, 1024, 0, stream>>>(cursor, row);
    fill_k<<<(N_EDGES + 255) / 256, 256, 0, stream>>>(ei, cursor, bucket);

    // ---- layer 1 ----
    gather1<<<N_NODES / 4, 256, 0, stream>>>(x, row, bucket, eps1, agg1);
    mlp1<<<N_NODES / NB, 128, 0, stream>>>(agg1, W1, b1, W2, b2, h1);

    // ---- layer 2 ---- (agg2 overlays agg1; written after mlp1 consumed agg1)
    gather2<<<N_NODES / 4, 256, 0, stream>>>(h1, row, bucket, eps2, agg2);
    mlp2<<<N_NODES / NB, 128, 0, stream>>>(agg2, W3, b3, W4, b4, out);
}

// Round 8
// 400.554 us; speedup vs baseline: 10.9684x; 1.2518x over previous
//
#include <hip/hip_runtime.h>

#define N_NODES 50000
#define N_EDGES 800000
#define IN_CH 64
#define HIDDEN 128
#define OUT_CH 64
#define NB 4      // nodes per MLP block
#define NCHUNK ((N_NODES + 255) / 256)   // 196 scan chunks

typedef unsigned short ushort_t;
typedef unsigned int uint_t;

__device__ __forceinline__ float bits2f(unsigned int u16) {
    union { unsigned int i; float f; } v;
    v.i = (u16 & 0xFFFFu) << 16;
    return v.f;
}

__device__ __forceinline__ ushort_t f2bits(float f) {
    union { float f; unsigned int i; } v;
    v.f = f;
    unsigned int x = v.i;
    if ((x & 0x7F800000u) == 0x7F800000u) return (ushort_t)(x >> 16); // inf/nan
    unsigned int r = (x + 0x7FFFu + ((x >> 16) & 1u)) >> 16;          // RNE
    return (ushort_t)r;
}

// ======================= CSR build (by dst) =======================

__global__ __launch_bounds__(256) void hist_k(const int* __restrict__ ei,
                                              int* __restrict__ deg) {
    int e = blockIdx.x * 256 + threadIdx.x;
    if (e >= N_EDGES) return;
    atomicAdd(&deg[ei[N_EDGES + e]], 1);
}

// stage A: per-chunk sum of degrees -> partial[b]
__global__ __launch_bounds__(256) void scan_a(const int* __restrict__ deg,
                                              int* __restrict__ partial) {
    __shared__ int wsum[4];
    int b = blockIdx.x;
    int i = b * 256 + threadIdx.x;
    int d = (i < N_NODES) ? deg[i] : 0;
#pragma unroll
    for (int off = 32; off >= 1; off >>= 1) d += __shfl_down(d, off, 64);
    if ((threadIdx.x & 63) == 0) wsum[threadIdx.x >> 6] = d;
    __syncthreads();
    if (threadIdx.x == 0)
        partial[b] = wsum[0] + wsum[1] + wsum[2] + wsum[3];
}

// stage B: exclusive scan of NCHUNK partials (single tiny block)
__global__ __launch_bounds__(256) void scan_b(int* __restrict__ partial,
                                              int* __restrict__ row) {
    __shared__ int s[256];
    int t = threadIdx.x;
    int v = (t < NCHUNK) ? partial[t] : 0;
    s[t] = v;
    __syncthreads();
#pragma unroll
    for (int off = 1; off < 256; off <<= 1) {
        int a = s[t];
        int u = (t >= off) ? s[t - off] : 0;
        __syncthreads();
        s[t] = a + u;
        __syncthreads();
    }
    if (t < NCHUNK) partial[t] = s[t] - v;   // exclusive
    if (t == 0) row[N_NODES] = N_EDGES;
}

// stage C: in-chunk exclusive scan + chunk offset -> row[], cursor[]
// (deg and cursor alias: each thread reads its own deg[i] before overwrite)
__global__ __launch_bounds__(256) void scan_c(int* __restrict__ deg_cursor,
                                              const int* __restrict__ partial,
                                              int* __restrict__ row) {
    __shared__ int s[256];
    int b = blockIdx.x;
    int t = threadIdx.x;
    int i = b * 256 + t;
    int d = (i < N_NODES) ? deg_cursor[i] : 0;
    s[t] = d;
    __syncthreads();
#pragma unroll
    for (int off = 1; off < 256; off <<= 1) {
        int a = s[t];
        int u = (t >= off) ? s[t - off] : 0;
        __syncthreads();
        s[t] = a + u;
        __syncthreads();
    }
    if (i < N_NODES) {
        int excl = s[t] - d + partial[b];
        row[i] = excl;
        deg_cursor[i] = excl;
    }
}

__global__ __launch_bounds__(256) void fill_k(const int* __restrict__ ei,
                                              int* __restrict__ cursor,
                                              int* __restrict__ bucket) {
    int e = blockIdx.x * 256 + threadIdx.x;
    if (e >= N_EDGES) return;
    int src = ei[e];
    int dst = ei[N_EDGES + e];
    int pos = atomicAdd(&cursor[dst], 1);
    bucket[pos] = src;
}

// ======================= gather aggregations =======================
// gather1: one wave per node, lane = channel (64ch f32).
__global__ __launch_bounds__(256) void gather1(const float* __restrict__ x,
                                               const int* __restrict__ row,
                                               const int* __restrict__ bucket,
                                               const float* __restrict__ eps1,
                                               float* __restrict__ h) {
    int wid = threadIdx.x >> 6;
    int lane = threadIdx.x & 63;
    int n = blockIdx.x * 4 + wid;
    float acc0 = (1.0f + eps1[0]) * x[(size_t)n * IN_CH + lane];
    float acc1 = 0.0f;
    int lo = row[n], hi = row[n + 1];
    int i = lo;
    for (; i + 1 < hi; i += 2) {
        int s0 = bucket[i], s1 = bucket[i + 1];
        acc0 += x[(size_t)s0 * IN_CH + lane];
        acc1 += x[(size_t)s1 * IN_CH + lane];
    }
    if (i < hi) acc0 += x[(size_t)bucket[i] * IN_CH + lane];
    h[(size_t)n * IN_CH + lane] = acc0 + acc1;
}

// gather2: one wave per node, lane handles 2 bf16 channels via one uint load.
__global__ __launch_bounds__(256) void gather2(const ushort_t* __restrict__ h1,
                                               const int* __restrict__ row,
                                               const int* __restrict__ bucket,
                                               const float* __restrict__ eps2,
                                               float* __restrict__ hbuf) {
    int wid = threadIdx.x >> 6;
    int lane = threadIdx.x & 63;
    int n = blockIdx.x * 4 + wid;
    const uint_t* h1u = (const uint_t*)h1;
    uint_t v = h1u[(size_t)n * 64 + lane];
    float se = 1.0f + eps2[0];
    float a0 = se * bits2f(v), a1 = se * bits2f(v >> 16);
    float b0 = 0.0f, b1 = 0.0f;
    int lo = row[n], hi = row[n + 1];
    int i = lo;
    for (; i + 1 < hi; i += 2) {
        int s0 = bucket[i], s1 = bucket[i + 1];
        uint_t u0 = h1u[(size_t)s0 * 64 + lane];
        uint_t u1 = h1u[(size_t)s1 * 64 + lane];
        a0 += bits2f(u0); a1 += bits2f(u0 >> 16);
        b0 += bits2f(u1); b1 += bits2f(u1 >> 16);
    }
    if (i < hi) {
        uint_t u = h1u[(size_t)bucket[i] * 64 + lane];
        a0 += bits2f(u); a1 += bits2f(u >> 16);
    }
    float2* outp = (float2*)(hbuf + (size_t)n * HIDDEN + 2 * lane);
    *outp = make_float2(a0 + b0, a1 + b1);
}

// ======================= fused MLPs =======================
__global__ __launch_bounds__(128) void mlp1(const float* __restrict__ h,
                                            const float* __restrict__ W1,
                                            const float* __restrict__ b1,
                                            const float* __restrict__ W2,
                                            const float* __restrict__ b2,
                                            ushort_t* __restrict__ h1) {
    __shared__ float hs[NB][IN_CH];
    __shared__ float ts[NB][HIDDEN];
    int n0 = blockIdx.x * NB;
    int j = threadIdx.x;
    for (int i = j; i < NB * IN_CH; i += 128) {
        int nn = i >> 6, kk = i & 63;
        hs[nn][kk] = h[(size_t)(n0 + nn) * IN_CH + kk];
    }
    __syncthreads();
    float acc[NB];
#pragma unroll
    for (int q = 0; q < NB; q++) acc[q] = b1[j];
#pragma unroll 8
    for (int k = 0; k < IN_CH; k++) {
        float w = W1[(size_t)k * HIDDEN + j];
#pragma unroll
        for (int q = 0; q < NB; q++) acc[q] = fmaf(hs[q][k], w, acc[q]);
    }
#pragma unroll
    for (int q = 0; q < NB; q++) ts[q][j] = fmaxf(acc[q], 0.0f);
    __syncthreads();
    float acc2[NB];
#pragma unroll
    for (int q = 0; q < NB; q++) acc2[q] = b2[j];
#pragma unroll 8
    for (int k = 0; k < HIDDEN; k++) {
        float w = W2[(size_t)k * HIDDEN + j];
#pragma unroll
        for (int q = 0; q < NB; q++) acc2[q] = fmaf(ts[q][k], w, acc2[q]);
    }
#pragma unroll
    for (int q = 0; q < NB; q++)
        h1[(size_t)(n0 + q) * HIDDEN + j] = f2bits(fmaxf(acc2[q], 0.0f));
}

__global__ __launch_bounds__(128) void mlp2(const float* __restrict__ h,
                                            const float* __restrict__ W3,
                                            const float* __restrict__ b3,
                                            const float* __restrict__ W4,
                                            const float* __restrict__ b4,
                                            float* __restrict__ out) {
    __shared__ float hs[NB][HIDDEN];
    __shared__ float ts[NB][HIDDEN];
    int n0 = blockIdx.x * NB;
    int j = threadIdx.x;
    for (int i = j; i < NB * HIDDEN; i += 128) {
        int nn = i >> 7, kk = i & 127;
        hs[nn][kk] = h[(size_t)(n0 + nn) * HIDDEN + kk];
    }
    __syncthreads();
    float acc[NB];
#pragma unroll
    for (int q = 0; q < NB; q++) acc[q] = b3[j];
#pragma unroll 8
    for (int k = 0; k < HIDDEN; k++) {
        float w = W3[(size_t)k * HIDDEN + j];
#pragma unroll
        for (int q = 0; q < NB; q++) acc[q] = fmaf(hs[q][k], w, acc[q]);
    }
#pragma unroll
    for (int q = 0; q < NB; q++) ts[q][j] = fmaxf(acc[q], 0.0f);
    __syncthreads();
    if (j < OUT_CH) {
        float acc2[NB];
#pragma unroll
        for (int q = 0; q < NB; q++) acc2[q] = b4[j];
#pragma unroll 8
        for (int k = 0; k < HIDDEN; k++) {
            float w = W4[(size_t)k * OUT_CH + j];
#pragma unroll
            for (int q = 0; q < NB; q++) acc2[q] = fmaf(ts[q][k], w, acc2[q]);
        }
#pragma unroll
        for (int q = 0; q < NB; q++)
            out[(size_t)(n0 + q) * OUT_CH + j] = acc2[q];
    }
}

extern "C" void kernel_launch(void* const* d_in, const int* in_sizes, int n_in,
                              void* d_out, int out_size, void* d_ws, size_t ws_size,
                              hipStream_t stream) {
    const float* x    = (const float*)d_in[0];
    const int*   ei   = (const int*)d_in[1];
    const float* W1   = (const float*)d_in[2];
    const float* b1   = (const float*)d_in[3];
    const float* W2   = (const float*)d_in[4];
    const float* b2   = (const float*)d_in[5];
    const float* eps1 = (const float*)d_in[6];
    const float* W3   = (const float*)d_in[7];
    const float* b3   = (const float*)d_in[8];
    const float* W4   = (const float*)d_in[9];
    const float* b4   = (const float*)d_in[10];
    const float* eps2 = (const float*)d_in[11];
    float* out = (float*)d_out;

    // Workspace layout (~42 MB):
    //   [0 .. 6.4M floats)      agg2/h-buf (agg1/h overlays first 3.2M)
    //   [6.4M .. 9.6M floats)   h1 as bf16 (6.4M ushorts)
    //   [9.6M .. 10.4M floats)  bucket (800K ints)
    //   then row (50001+pad), cursor/deg (50000), partial (256)
    float* ws   = (float*)d_ws;
    float* agg1 = ws;
    float* agg2 = ws;
    ushort_t* h1 = (ushort_t*)(ws + (size_t)N_NODES * HIDDEN);
    int* bucket  = (int*)(ws + (size_t)N_NODES * HIDDEN + (size_t)N_NODES * HIDDEN / 2);
    int* row     = bucket + N_EDGES;
    int* cursor  = row + N_NODES + 4;
    int* partial = cursor + N_NODES;

    // ---- CSR build ----
    hipMemsetAsync(cursor, 0, N_NODES * sizeof(int), stream);
    hist_k<<<(N_EDGES + 255) / 256, 256, 0, stream>>>(ei, cursor);
    scan_a<<<NCHUNK, 256, 0, stream>>>(cursor, partial);
    scan_b<<<1, 256, 0, stream>>>(partial, row);
    scan_c<<<NCHUNK, 256, 0, stream>>>(cursor, partial, row);
    fill_k<<<(N_EDGES + 255) / 256, 256, 0, stream>>>(ei, cursor, bucket);

    // ---- layer 1 ----
    gather1<<<N_NODES / 4, 256, 0, stream>>>(x, row, bucket, eps1, agg1);
    mlp1<<<N_NODES / NB, 128, 0, stream>>>(agg1, W1, b1, W2, b2, h1);

    // ---- layer 2 ----
    gather2<<<N_NODES / 4, 256, 0, stream>>>(h1, row, bucket, eps2, agg2);
    mlp2<<<N_NODES / NB, 128, 0, stream>>>(agg2, W3, b3, W4, b4, out);
}

// Round 9
// 393.875 us; speedup vs baseline: 11.1544x; 1.0170x over previous
//
#include <hip/hip_runtime.h>

#define N_NODES 50000
#define N_EDGES 800000
#define IN_CH 64
#define HIDDEN 128
#define OUT_CH 64
#define NBM 16    // nodes per MLP block (50000/16 = 3125)
#define NCHUNK ((N_NODES + 255) / 256)   // 196 scan chunks

typedef unsigned short ushort_t;
typedef unsigned int uint_t;

__device__ __forceinline__ float bits2f(unsigned int u16) {
    union { unsigned int i; float f; } v;
    v.i = (u16 & 0xFFFFu) << 16;
    return v.f;
}

__device__ __forceinline__ ushort_t f2bits(float f) {
    union { float f; unsigned int i; } v;
    v.f = f;
    unsigned int x = v.i;
    if ((x & 0x7F800000u) == 0x7F800000u) return (ushort_t)(x >> 16); // inf/nan
    unsigned int r = (x + 0x7FFFu + ((x >> 16) & 1u)) >> 16;          // RNE
    return (ushort_t)r;
}

// ======================= CSR build (by dst) =======================

__global__ __launch_bounds__(256) void hist_k(const int* __restrict__ ei,
                                              int* __restrict__ deg) {
    int e = blockIdx.x * 256 + threadIdx.x;
    if (e >= N_EDGES) return;
    atomicAdd(&deg[ei[N_EDGES + e]], 1);
}

__global__ __launch_bounds__(256) void scan_a(const int* __restrict__ deg,
                                              int* __restrict__ partial) {
    __shared__ int wsum[4];
    int b = blockIdx.x;
    int i = b * 256 + threadIdx.x;
    int d = (i < N_NODES) ? deg[i] : 0;
#pragma unroll
    for (int off = 32; off >= 1; off >>= 1) d += __shfl_down(d, off, 64);
    if ((threadIdx.x & 63) == 0) wsum[threadIdx.x >> 6] = d;
    __syncthreads();
    if (threadIdx.x == 0)
        partial[b] = wsum[0] + wsum[1] + wsum[2] + wsum[3];
}

__global__ __launch_bounds__(256) void scan_b(int* __restrict__ partial,
                                              int* __restrict__ row) {
    __shared__ int s[256];
    int t = threadIdx.x;
    int v = (t < NCHUNK) ? partial[t] : 0;
    s[t] = v;
    __syncthreads();
#pragma unroll
    for (int off = 1; off < 256; off <<= 1) {
        int a = s[t];
        int u = (t >= off) ? s[t - off] : 0;
        __syncthreads();
        s[t] = a + u;
        __syncthreads();
    }
    if (t < NCHUNK) partial[t] = s[t] - v;   // exclusive
    if (t == 0) row[N_NODES] = N_EDGES;
}

__global__ __launch_bounds__(256) void scan_c(int* __restrict__ deg_cursor,
                                              const int* __restrict__ partial,
                                              int* __restrict__ row) {
    __shared__ int s[256];
    int b = blockIdx.x;
    int t = threadIdx.x;
    int i = b * 256 + t;
    int d = (i < N_NODES) ? deg_cursor[i] : 0;
    s[t] = d;
    __syncthreads();
#pragma unroll
    for (int off = 1; off < 256; off <<= 1) {
        int a = s[t];
        int u = (t >= off) ? s[t - off] : 0;
        __syncthreads();
        s[t] = a + u;
        __syncthreads();
    }
    if (i < N_NODES) {
        int excl = s[t] - d + partial[b];
        row[i] = excl;
        deg_cursor[i] = excl;
    }
}

__global__ __launch_bounds__(256) void fill_k(const int* __restrict__ ei,
                                              int* __restrict__ cursor,
                                              int* __restrict__ bucket) {
    int e = blockIdx.x * 256 + threadIdx.x;
    if (e >= N_EDGES) return;
    int src = ei[e];
    int dst = ei[N_EDGES + e];
    int pos = atomicAdd(&cursor[dst], 1);
    bucket[pos] = src;
}

// ======================= x -> bf16 convert =======================
__global__ __launch_bounds__(256) void cvt_k(const float* __restrict__ x,
                                             uint_t* __restrict__ xu) {
    int i = blockIdx.x * 256 + threadIdx.x;     // over bf16 pairs
    if (i >= N_NODES * IN_CH / 2) return;
    float2 v = ((const float2*)x)[i];
    xu[i] = (uint_t)f2bits(v.x) | ((uint_t)f2bits(v.y) << 16);
}

// ======================= gather aggregations =======================
// gather1: wave per node; lanes 0-31 even edges, 32-63 odd edges; 2 bf16 ch/lane.
__global__ __launch_bounds__(256) void gather1(const uint_t* __restrict__ xu,
                                               const int* __restrict__ row,
                                               const int* __restrict__ bucket,
                                               const float* __restrict__ eps1,
                                               float* __restrict__ h) {
    int wid = threadIdx.x >> 6;
    int lane = threadIdx.x & 63;
    int half = lane >> 5;
    int li = lane & 31;
    int n = blockIdx.x * 4 + wid;
    float a0 = 0.0f, a1 = 0.0f;
    if (half == 0) {
        uint_t v = xu[(size_t)n * 32 + li];
        float se = 1.0f + eps1[0];
        a0 = se * bits2f(v);
        a1 = se * bits2f(v >> 16);
    }
    int lo = row[n], hi = row[n + 1];
    for (int i = lo + half; i < hi; i += 2) {
        uint_t u = xu[(size_t)bucket[i] * 32 + li];
        a0 += bits2f(u);
        a1 += bits2f(u >> 16);
    }
    float p0 = __shfl(a0, lane ^ 32);
    float p1 = __shfl(a1, lane ^ 32);
    if (half == 0) {
        float2* outp = (float2*)(h + (size_t)n * IN_CH + 2 * li);
        *outp = make_float2(a0 + p0, a1 + p1);
    }
}

// gather2: wave per node; lane = uint index (2 bf16 ch) over 128 channels.
__global__ __launch_bounds__(256) void gather2(const ushort_t* __restrict__ h1,
                                               const int* __restrict__ row,
                                               const int* __restrict__ bucket,
                                               const float* __restrict__ eps2,
                                               float* __restrict__ hbuf) {
    int wid = threadIdx.x >> 6;
    int lane = threadIdx.x & 63;
    int n = blockIdx.x * 4 + wid;
    const uint_t* h1u = (const uint_t*)h1;
    uint_t v = h1u[(size_t)n * 64 + lane];
    float se = 1.0f + eps2[0];
    float a0 = se * bits2f(v), a1 = se * bits2f(v >> 16);
    float b0 = 0.0f, b1 = 0.0f;
    int lo = row[n], hi = row[n + 1];
    int i = lo;
    for (; i + 1 < hi; i += 2) {
        int s0 = bucket[i], s1 = bucket[i + 1];
        uint_t u0 = h1u[(size_t)s0 * 64 + lane];
        uint_t u1 = h1u[(size_t)s1 * 64 + lane];
        a0 += bits2f(u0); a1 += bits2f(u0 >> 16);
        b0 += bits2f(u1); b1 += bits2f(u1 >> 16);
    }
    if (i < hi) {
        uint_t u = h1u[(size_t)bucket[i] * 64 + lane];
        a0 += bits2f(u); a1 += bits2f(u >> 16);
    }
    float2* outp = (float2*)(hbuf + (size_t)n * HIDDEN + 2 * lane);
    *outp = make_float2(a0 + b0, a1 + b1);
}

// ======================= fused MLPs (NBM nodes/block) =======================
// mlp1: h1 = relu( relu(h@W1+b1) @ W2 + b2 )  -> bf16
__global__ __launch_bounds__(128) void mlp1(const float* __restrict__ h,
                                            const float* __restrict__ W1,
                                            const float* __restrict__ b1,
                                            const float* __restrict__ W2,
                                            const float* __restrict__ b2,
                                            ushort_t* __restrict__ h1) {
    __shared__ float hs[NBM][IN_CH];    // 4 KB
    __shared__ float ts[NBM][HIDDEN];   // 8 KB
    int n0 = blockIdx.x * NBM;
    int j = threadIdx.x;
    for (int i = j; i < NBM * IN_CH; i += 128)
        ((float*)hs)[i] = h[(size_t)n0 * IN_CH + i];
    __syncthreads();
    float acc[NBM];
    float bj = b1[j];
#pragma unroll
    for (int q = 0; q < NBM; q++) acc[q] = bj;
    for (int kb = 0; kb < IN_CH; kb += 4) {
        float w0 = W1[(kb + 0) * HIDDEN + j], w1 = W1[(kb + 1) * HIDDEN + j];
        float w2 = W1[(kb + 2) * HIDDEN + j], w3 = W1[(kb + 3) * HIDDEN + j];
#pragma unroll
        for (int q = 0; q < NBM; q++) {
            float4 hv = *reinterpret_cast<const float4*>(&hs[q][kb]);
            acc[q] = fmaf(hv.x, w0, acc[q]);
            acc[q] = fmaf(hv.y, w1, acc[q]);
            acc[q] = fmaf(hv.z, w2, acc[q]);
            acc[q] = fmaf(hv.w, w3, acc[q]);
        }
    }
#pragma unroll
    for (int q = 0; q < NBM; q++) ts[q][j] = fmaxf(acc[q], 0.0f);
    __syncthreads();
    float acc2[NBM];
    float bj2 = b2[j];
#pragma unroll
    for (int q = 0; q < NBM; q++) acc2[q] = bj2;
    for (int kb = 0; kb < HIDDEN; kb += 4) {
        float w0 = W2[(kb + 0) * HIDDEN + j], w1 = W2[(kb + 1) * HIDDEN + j];
        float w2 = W2[(kb + 2) * HIDDEN + j], w3 = W2[(kb + 3) * HIDDEN + j];
#pragma unroll
        for (int q = 0; q < NBM; q++) {
            float4 tv = *reinterpret_cast<const float4*>(&ts[q][kb]);
            acc2[q] = fmaf(tv.x, w0, acc2[q]);
            acc2[q] = fmaf(tv.y, w1, acc2[q]);
            acc2[q] = fmaf(tv.z, w2, acc2[q]);
            acc2[q] = fmaf(tv.w, w3, acc2[q]);
        }
    }
#pragma unroll
    for (int q = 0; q < NBM; q++)
        h1[(size_t)(n0 + q) * HIDDEN + j] = f2bits(fmaxf(acc2[q], 0.0f));
}

// mlp2: out = relu(h@W3+b3) @ W4 + b4  -> f32
// stage 2: 64 cols; threads 0-63 -> nodes q0=0..7, threads 64-127 -> q0=8..15
__global__ __launch_bounds__(128) void mlp2(const float* __restrict__ h,
                                            const float* __restrict__ W3,
                                            const float* __restrict__ b3,
                                            const float* __restrict__ W4,
                                            const float* __restrict__ b4,
                                            float* __restrict__ out) {
    __shared__ float hs[NBM][HIDDEN];   // 8 KB
    __shared__ float ts[NBM][HIDDEN];   // 8 KB
    int n0 = blockIdx.x * NBM;
    int j = threadIdx.x;
    for (int i = j; i < NBM * HIDDEN; i += 128)
        ((float*)hs)[i] = h[(size_t)n0 * HIDDEN + i];
    __syncthreads();
    float acc[NBM];
    float bj = b3[j];
#pragma unroll
    for (int q = 0; q < NBM; q++) acc[q] = bj;
    for (int kb = 0; kb < HIDDEN; kb += 4) {
        float w0 = W3[(kb + 0) * HIDDEN + j], w1 = W3[(kb + 1) * HIDDEN + j];
        float w2 = W3[(kb + 2) * HIDDEN + j], w3 = W3[(kb + 3) * HIDDEN + j];
#pragma unroll
        for (int q = 0; q < NBM; q++) {
            float4 hv = *reinterpret_cast<const float4*>(&hs[q][kb]);
            acc[q] = fmaf(hv.x, w0, acc[q]);
            acc[q] = fmaf(hv.y, w1, acc[q]);
            acc[q] = fmaf(hv.z, w2, acc[q]);
            acc[q] = fmaf(hv.w, w3, acc[q]);
        }
    }
#pragma unroll
    for (int q = 0; q < NBM; q++) ts[q][j] = fmaxf(acc[q], 0.0f);
    __syncthreads();
    int jc = j & 63;
    int q0 = (j >> 6) * 8;
    float acc2[8];
    float bj2 = b4[jc];
#pragma unroll
    for (int q = 0; q < 8; q++) acc2[q] = bj2;
    for (int kb = 0; kb < HIDDEN; kb += 4) {
        float w0 = W4[(kb + 0) * OUT_CH + jc], w1 = W4[(kb + 1) * OUT_CH + jc];
        float w2 = W4[(kb + 2) * OUT_CH + jc], w3 = W4[(kb + 3) * OUT_CH + jc];
#pragma unroll
        for (int q = 0; q < 8; q++) {
            float4 tv = *reinterpret_cast<const float4*>(&ts[q0 + q][kb]);
            acc2[q] = fmaf(tv.x, w0, acc2[q]);
            acc2[q] = fmaf(tv.y, w1, acc2[q]);
            acc2[q] = fmaf(tv.z, w2, acc2[q]);
            acc2[q] = fmaf(tv.w, w3, acc2[q]);
        }
    }
#pragma unroll
    for (int q = 0; q < 8; q++)
        out[(size_t)(n0 + q0 + q) * OUT_CH + jc] = acc2[q];
}

extern "C" void kernel_launch(void* const* d_in, const int* in_sizes, int n_in,
                              void* d_out, int out_size, void* d_ws, size_t ws_size,
                              hipStream_t stream) {
    const float* x    = (const float*)d_in[0];
    const int*   ei   = (const int*)d_in[1];
    const float* W1   = (const float*)d_in[2];
    const float* b1   = (const float*)d_in[3];
    const float* W2   = (const float*)d_in[4];
    const float* b2   = (const float*)d_in[5];
    const float* eps1 = (const float*)d_in[6];
    const float* W3   = (const float*)d_in[7];
    const float* b3   = (const float*)d_in[8];
    const float* W4   = (const float*)d_in[9];
    const float* b4   = (const float*)d_in[10];
    const float* eps2 = (const float*)d_in[11];
    float* out = (float*)d_out;

    // Workspace (~42 MB):
    //   [0 .. 6.4M floats)      agg2/h2-buf (agg1/h overlays first 3.2M floats)
    //   [6.4M .. 9.6M floats)   bufA: xb (first 3.2M ushorts) then h1 (6.4M ushorts)
    //   [9.6M .. 10.4M floats)  bucket (800K ints)
    //   then row (50001+pad), cursor/deg (50000), partial (256)
    float* ws   = (float*)d_ws;
    float* agg1 = ws;
    float* agg2 = ws;
    ushort_t* bufA = (ushort_t*)(ws + (size_t)N_NODES * HIDDEN);
    uint_t* xb     = (uint_t*)bufA;          // used only before mlp1 writes h1
    ushort_t* h1   = bufA;
    int* bucket  = (int*)(ws + (size_t)N_NODES * HIDDEN + (size_t)N_NODES * HIDDEN / 2);
    int* row     = bucket + N_EDGES;
    int* cursor  = row + N_NODES + 4;
    int* partial = cursor + N_NODES;

    // ---- CSR build ----
    hipMemsetAsync(cursor, 0, N_NODES * sizeof(int), stream);
    hist_k<<<(N_EDGES + 255) / 256, 256, 0, stream>>>(ei, cursor);
    scan_a<<<NCHUNK, 256, 0, stream>>>(cursor, partial);
    scan_b<<<1, 256, 0, stream>>>(partial, row);
    scan_c<<<NCHUNK, 256, 0, stream>>>(cursor, partial, row);
    fill_k<<<(N_EDGES + 255) / 256, 256, 0, stream>>>(ei, cursor, bucket);

    // ---- layer 1 ----
    cvt_k<<<(N_NODES * IN_CH / 2 + 255) / 256, 256, 0, stream>>>(x, xb);
    gather1<<<N_NODES / 4, 256, 0, stream>>>(xb, row, bucket, eps1, agg1);
    mlp1<<<N_NODES / NBM, 128, 0, stream>>>(agg1, W1, b1, W2, b2, h1);

    // ---- layer 2 ----
    gather2<<<N_NODES / 4, 256, 0, stream>>>(h1, row, bucket, eps2, agg2);
    mlp2<<<N_NODES / NBM, 128, 0, stream>>>(agg2, W3, b3, W4, b4, out);
}

// Round 10
// 374.313 us; speedup vs baseline: 11.7373x; 1.0523x over previous
//
#include <hip/hip_runtime.h>

#define N_NODES 50000
#define N_EDGES 800000
#define IN_CH 64
#define HIDDEN 128
#define OUT_CH 64
#define NBM 16    // nodes per MLP block (50000/16 = 3125)
#define NCHUNK ((N_NODES + 255) / 256)   // 196 scan chunks

typedef unsigned short ushort_t;
typedef unsigned int uint_t;

__device__ __forceinline__ float bits2f(unsigned int u16) {
    union { unsigned int i; float f; } v;
    v.i = (u16 & 0xFFFFu) << 16;
    return v.f;
}

__device__ __forceinline__ ushort_t f2bits(float f) {
    union { float f; unsigned int i; } v;
    v.f = f;
    unsigned int x = v.i;
    if ((x & 0x7F800000u) == 0x7F800000u) return (ushort_t)(x >> 16); // inf/nan
    unsigned int r = (x + 0x7FFFu + ((x >> 16) & 1u)) >> 16;          // RNE
    return (ushort_t)r;
}

// ======================= CSR build (by dst) =======================

__global__ __launch_bounds__(256) void hist_k(const int* __restrict__ ei,
                                              int* __restrict__ deg) {
    int e = blockIdx.x * 256 + threadIdx.x;
    if (e >= N_EDGES) return;
    atomicAdd(&deg[ei[N_EDGES + e]], 1);
}

__global__ __launch_bounds__(256) void scan_a(const int* __restrict__ deg,
                                              int* __restrict__ partial) {
    __shared__ int wsum[4];
    int b = blockIdx.x;
    int i = b * 256 + threadIdx.x;
    int d = (i < N_NODES) ? deg[i] : 0;
#pragma unroll
    for (int off = 32; off >= 1; off >>= 1) d += __shfl_down(d, off, 64);
    if ((threadIdx.x & 63) == 0) wsum[threadIdx.x >> 6] = d;
    __syncthreads();
    if (threadIdx.x == 0)
        partial[b] = wsum[0] + wsum[1] + wsum[2] + wsum[3];
}

__global__ __launch_bounds__(256) void scan_b(int* __restrict__ partial,
                                              int* __restrict__ row) {
    __shared__ int s[256];
    int t = threadIdx.x;
    int v = (t < NCHUNK) ? partial[t] : 0;
    s[t] = v;
    __syncthreads();
#pragma unroll
    for (int off = 1; off < 256; off <<= 1) {
        int a = s[t];
        int u = (t >= off) ? s[t - off] : 0;
        __syncthreads();
        s[t] = a + u;
        __syncthreads();
    }
    if (t < NCHUNK) partial[t] = s[t] - v;   // exclusive
    if (t == 0) row[N_NODES] = N_EDGES;
}

__global__ __launch_bounds__(256) void scan_c(int* __restrict__ deg_cursor,
                                              const int* __restrict__ partial,
                                              int* __restrict__ row) {
    __shared__ int s[256];
    int b = blockIdx.x;
    int t = threadIdx.x;
    int i = b * 256 + t;
    int d = (i < N_NODES) ? deg_cursor[i] : 0;
    s[t] = d;
    __syncthreads();
#pragma unroll
    for (int off = 1; off < 256; off <<= 1) {
        int a = s[t];
        int u = (t >= off) ? s[t - off] : 0;
        __syncthreads();
        s[t] = a + u;
        __syncthreads();
    }
    if (i < N_NODES) {
        int excl = s[t] - d + partial[b];
        row[i] = excl;
        deg_cursor[i] = excl;
    }
}

__global__ __launch_bounds__(256) void fill_k(const int* __restrict__ ei,
                                              int* __restrict__ cursor,
                                              int* __restrict__ bucket) {
    int e = blockIdx.x * 256 + threadIdx.x;
    if (e >= N_EDGES) return;
    int src = ei[e];
    int dst = ei[N_EDGES + e];
    int pos = atomicAdd(&cursor[dst], 1);
    bucket[pos] = src;
}

// ======================= x -> bf16 convert =======================
__global__ __launch_bounds__(256) void cvt_k(const float* __restrict__ x,
                                             uint_t* __restrict__ xu) {
    int i = blockIdx.x * 256 + threadIdx.x;     // over bf16 pairs
    if (i >= N_NODES * IN_CH / 2) return;
    float2 v = ((const float2*)x)[i];
    xu[i] = (uint_t)f2bits(v.x) | ((uint_t)f2bits(v.y) << 16);
}

// ======================= gather aggregations =======================
__global__ __launch_bounds__(256) void gather1(const uint_t* __restrict__ xu,
                                               const int* __restrict__ row,
                                               const int* __restrict__ bucket,
                                               const float* __restrict__ eps1,
                                               float* __restrict__ h) {
    int wid = threadIdx.x >> 6;
    int lane = threadIdx.x & 63;
    int half = lane >> 5;
    int li = lane & 31;
    int n = blockIdx.x * 4 + wid;
    float a0 = 0.0f, a1 = 0.0f;
    if (half == 0) {
        uint_t v = xu[(size_t)n * 32 + li];
        float se = 1.0f + eps1[0];
        a0 = se * bits2f(v);
        a1 = se * bits2f(v >> 16);
    }
    int lo = row[n], hi = row[n + 1];
    for (int i = lo + half; i < hi; i += 2) {
        uint_t u = xu[(size_t)bucket[i] * 32 + li];
        a0 += bits2f(u);
        a1 += bits2f(u >> 16);
    }
    float p0 = __shfl(a0, lane ^ 32);
    float p1 = __shfl(a1, lane ^ 32);
    if (half == 0) {
        float2* outp = (float2*)(h + (size_t)n * IN_CH + 2 * li);
        *outp = make_float2(a0 + p0, a1 + p1);
    }
}

__global__ __launch_bounds__(256) void gather2(const ushort_t* __restrict__ h1,
                                               const int* __restrict__ row,
                                               const int* __restrict__ bucket,
                                               const float* __restrict__ eps2,
                                               float* __restrict__ hbuf) {
    int wid = threadIdx.x >> 6;
    int lane = threadIdx.x & 63;
    int n = blockIdx.x * 4 + wid;
    const uint_t* h1u = (const uint_t*)h1;
    uint_t v = h1u[(size_t)n * 64 + lane];
    float se = 1.0f + eps2[0];
    float a0 = se * bits2f(v), a1 = se * bits2f(v >> 16);
    float b0 = 0.0f, b1 = 0.0f;
    int lo = row[n], hi = row[n + 1];
    int i = lo;
    for (; i + 1 < hi; i += 2) {
        int s0 = bucket[i], s1 = bucket[i + 1];
        uint_t u0 = h1u[(size_t)s0 * 64 + lane];
        uint_t u1 = h1u[(size_t)s1 * 64 + lane];
        a0 += bits2f(u0); a1 += bits2f(u0 >> 16);
        b0 += bits2f(u1); b1 += bits2f(u1 >> 16);
    }
    if (i < hi) {
        uint_t u = h1u[(size_t)bucket[i] * 64 + lane];
        a0 += bits2f(u); a1 += bits2f(u >> 16);
    }
    float2* outp = (float2*)(hbuf + (size_t)n * HIDDEN + 2 * lane);
    *outp = make_float2(a0 + b0, a1 + b1);
}

// ======================= fused MLPs (NBM nodes/block, 4x4 micro-tiles) ======
__device__ __forceinline__ void fma4(float4& acc, const float4& hv,
                                     const float4& w0, const float4& w1,
                                     const float4& w2, const float4& w3) {
    acc.x = fmaf(hv.x, w0.x, acc.x); acc.y = fmaf(hv.x, w0.y, acc.y);
    acc.z = fmaf(hv.x, w0.z, acc.z); acc.w = fmaf(hv.x, w0.w, acc.w);
    acc.x = fmaf(hv.y, w1.x, acc.x); acc.y = fmaf(hv.y, w1.y, acc.y);
    acc.z = fmaf(hv.y, w1.z, acc.z); acc.w = fmaf(hv.y, w1.w, acc.w);
    acc.x = fmaf(hv.z, w2.x, acc.x); acc.y = fmaf(hv.z, w2.y, acc.y);
    acc.z = fmaf(hv.z, w2.z, acc.z); acc.w = fmaf(hv.z, w2.w, acc.w);
    acc.x = fmaf(hv.w, w3.x, acc.x); acc.y = fmaf(hv.w, w3.y, acc.y);
    acc.z = fmaf(hv.w, w3.z, acc.z); acc.w = fmaf(hv.w, w3.w, acc.w);
}

// mlp1: h1 = relu( relu(h@W1+b1) @ W2 + b2 )  -> bf16
__global__ __launch_bounds__(128) void mlp1(const float* __restrict__ h,
                                            const float* __restrict__ W1,
                                            const float* __restrict__ b1,
                                            const float* __restrict__ W2,
                                            const float* __restrict__ b2,
                                            ushort_t* __restrict__ h1) {
    __shared__ float hs[NBM][IN_CH];    // 4 KB
    __shared__ float ts[NBM][HIDDEN];   // 8 KB
    int n0 = blockIdx.x * NBM;
    int t = threadIdx.x;
    for (int i = t; i < NBM * IN_CH / 4; i += 128)
        ((float4*)hs)[i] = ((const float4*)(h + (size_t)n0 * IN_CH))[i];
    __syncthreads();
    int j0 = (t & 31) * 4;          // 4 cols
    int q0 = (t >> 5) * 4;          // 4 nodes
    // stage 1: K=64, C=128
    float4 acc[4];
    {
        float4 bv = *(const float4*)&b1[j0];
        acc[0] = bv; acc[1] = bv; acc[2] = bv; acc[3] = bv;
    }
    for (int kb = 0; kb < IN_CH; kb += 4) {
        float4 w0 = *(const float4*)&W1[(size_t)(kb + 0) * HIDDEN + j0];
        float4 w1 = *(const float4*)&W1[(size_t)(kb + 1) * HIDDEN + j0];
        float4 w2 = *(const float4*)&W1[(size_t)(kb + 2) * HIDDEN + j0];
        float4 w3 = *(const float4*)&W1[(size_t)(kb + 3) * HIDDEN + j0];
#pragma unroll
        for (int q = 0; q < 4; q++) {
            float4 hv = *(const float4*)&hs[q0 + q][kb];
            fma4(acc[q], hv, w0, w1, w2, w3);
        }
    }
#pragma unroll
    for (int q = 0; q < 4; q++) {
        float4 r = acc[q];
        r.x = fmaxf(r.x, 0.f); r.y = fmaxf(r.y, 0.f);
        r.z = fmaxf(r.z, 0.f); r.w = fmaxf(r.w, 0.f);
        *(float4*)&ts[q0 + q][j0] = r;
    }
    __syncthreads();
    // stage 2: K=128, C=128
    float4 acc2[4];
    {
        float4 bv = *(const float4*)&b2[j0];
        acc2[0] = bv; acc2[1] = bv; acc2[2] = bv; acc2[3] = bv;
    }
    for (int kb = 0; kb < HIDDEN; kb += 4) {
        float4 w0 = *(const float4*)&W2[(size_t)(kb + 0) * HIDDEN + j0];
        float4 w1 = *(const float4*)&W2[(size_t)(kb + 1) * HIDDEN + j0];
        float4 w2 = *(const float4*)&W2[(size_t)(kb + 2) * HIDDEN + j0];
        float4 w3 = *(const float4*)&W2[(size_t)(kb + 3) * HIDDEN + j0];
#pragma unroll
        for (int q = 0; q < 4; q++) {
            float4 tv = *(const float4*)&ts[q0 + q][kb];
            fma4(acc2[q], tv, w0, w1, w2, w3);
        }
    }
#pragma unroll
    for (int q = 0; q < 4; q++) {
        float4 r = acc2[q];
        uint_t lo = (uint_t)f2bits(fmaxf(r.x, 0.f)) | ((uint_t)f2bits(fmaxf(r.y, 0.f)) << 16);
        uint_t hi = (uint_t)f2bits(fmaxf(r.z, 0.f)) | ((uint_t)f2bits(fmaxf(r.w, 0.f)) << 16);
        *(uint2*)&h1[(size_t)(n0 + q0 + q) * HIDDEN + j0] = make_uint2(lo, hi);
    }
}

// mlp2: out = relu(h@W3+b3) @ W4 + b4  -> f32
__global__ __launch_bounds__(128) void mlp2(const float* __restrict__ h,
                                            const float* __restrict__ W3,
                                            const float* __restrict__ b3,
                                            const float* __restrict__ W4,
                                            const float* __restrict__ b4,
                                            float* __restrict__ out) {
    __shared__ float hs[NBM][HIDDEN];   // 8 KB
    __shared__ float ts[NBM][HIDDEN];   // 8 KB
    int n0 = blockIdx.x * NBM;
    int t = threadIdx.x;
    for (int i = t; i < NBM * HIDDEN / 4; i += 128)
        ((float4*)hs)[i] = ((const float4*)(h + (size_t)n0 * HIDDEN))[i];
    __syncthreads();
    // stage 1: K=128, C=128
    int j0 = (t & 31) * 4;
    int q0 = (t >> 5) * 4;
    float4 acc[4];
    {
        float4 bv = *(const float4*)&b3[j0];
        acc[0] = bv; acc[1] = bv; acc[2] = bv; acc[3] = bv;
    }
    for (int kb = 0; kb < HIDDEN; kb += 4) {
        float4 w0 = *(const float4*)&W3[(size_t)(kb + 0) * HIDDEN + j0];
        float4 w1 = *(const float4*)&W3[(size_t)(kb + 1) * HIDDEN + j0];
        float4 w2 = *(const float4*)&W3[(size_t)(kb + 2) * HIDDEN + j0];
        float4 w3 = *(const float4*)&W3[(size_t)(kb + 3) * HIDDEN + j0];
#pragma unroll
        for (int q = 0; q < 4; q++) {
            float4 hv = *(const float4*)&hs[q0 + q][kb];
            fma4(acc[q], hv, w0, w1, w2, w3);
        }
    }
#pragma unroll
    for (int q = 0; q < 4; q++) {
        float4 r = acc[q];
        r.x = fmaxf(r.x, 0.f); r.y = fmaxf(r.y, 0.f);
        r.z = fmaxf(r.z, 0.f); r.w = fmaxf(r.w, 0.f);
        *(float4*)&ts[q0 + q][j0] = r;
    }
    __syncthreads();
    // stage 2: K=128, C=64 -> 4 cols x 2 nodes per thread
    int j2 = (t & 15) * 4;
    int q2 = (t >> 4) * 2;
    float4 acc2[2];
    {
        float4 bv = *(const float4*)&b4[j2];
        acc2[0] = bv; acc2[1] = bv;
    }
    for (int kb = 0; kb < HIDDEN; kb += 4) {
        float4 w0 = *(const float4*)&W4[(size_t)(kb + 0) * OUT_CH + j2];
        float4 w1 = *(const float4*)&W4[(size_t)(kb + 1) * OUT_CH + j2];
        float4 w2 = *(const float4*)&W4[(size_t)(kb + 2) * OUT_CH + j2];
        float4 w3 = *(const float4*)&W4[(size_t)(kb + 3) * OUT_CH + j2];
#pragma unroll
        for (int q = 0; q < 2; q++) {
            float4 tv = *(const float4*)&ts[q2 + q][kb];
            fma4(acc2[q], tv, w0, w1, w2, w3);
        }
    }
#pragma unroll
    for (int q = 0; q < 2; q++)
        *(float4*)&out[(size_t)(n0 + q2 + q) * OUT_CH + j2] = acc2[q];
}

extern "C" void kernel_launch(void* const* d_in, const int* in_sizes, int n_in,
                              void* d_out, int out_size, void* d_ws, size_t ws_size,
                              hipStream_t stream) {
    const float* x    = (const float*)d_in[0];
    const int*   ei   = (const int*)d_in[1];
    const float* W1   = (const float*)d_in[2];
    const float* b1   = (const float*)d_in[3];
    const float* W2   = (const float*)d_in[4];
    const float* b2   = (const float*)d_in[5];
    const float* eps1 = (const float*)d_in[6];
    const float* W3   = (const float*)d_in[7];
    const float* b3   = (const float*)d_in[8];
    const float* W4   = (const float*)d_in[9];
    const float* b4   = (const float*)d_in[10];
    const float* eps2 = (const float*)d_in[11];
    float* out = (float*)d_out;

    float* ws   = (float*)d_ws;
    float* agg1 = ws;
    float* agg2 = ws;
    ushort_t* bufA = (ushort_t*)(ws + (size_t)N_NODES * HIDDEN);
    uint_t* xb     = (uint_t*)bufA;          // used only before mlp1 writes h1
    ushort_t* h1   = bufA;
    int* bucket  = (int*)(ws + (size_t)N_NODES * HIDDEN + (size_t)N_NODES * HIDDEN / 2);
    int* row     = bucket + N_EDGES;
    int* cursor  = row + N_NODES + 4;
    int* partial = cursor + N_NODES;

    // ---- CSR build ----
    hipMemsetAsync(cursor, 0, N_NODES * sizeof(int), stream);
    hist_k<<<(N_EDGES + 255) / 256, 256, 0, stream>>>(ei, cursor);
    scan_a<<<NCHUNK, 256, 0, stream>>>(cursor, partial);
    scan_b<<<1, 256, 0, stream>>>(partial, row);
    scan_c<<<NCHUNK, 256, 0, stream>>>(cursor, partial, row);
    fill_k<<<(N_EDGES + 255) / 256, 256, 0, stream>>>(ei, cursor, bucket);

    // ---- layer 1 ----
    cvt_k<<<(N_NODES * IN_CH / 2 + 255) / 256, 256, 0, stream>>>(x, xb);
    gather1<<<N_NODES / 4, 256, 0, stream>>>(xb, row, bucket, eps1, agg1);
    mlp1<<<N_NODES / NBM, 128, 0, stream>>>(agg1, W1, b1, W2, b2, h1);

    // ---- layer 2 ----
    gather2<<<N_NODES / 4, 256, 0, stream>>>(h1, row, bucket, eps2, agg2);
    mlp2<<<N_NODES / NBM, 128, 0, stream>>>(agg2, W3, b3, W4, b4, out);
}

// Round 11
// 372.837 us; speedup vs baseline: 11.7838x; 1.0040x over previous
//
#include <hip/hip_runtime.h>

#define N_NODES 50000
#define N_EDGES 800000
#define IN_CH 64
#define HIDDEN 128
#define OUT_CH 64
#define NBM 32    // nodes per MLP block; grid 1563, tail block guarded
#define NCHUNK ((N_NODES + 255) / 256)   // 196 scan chunks

typedef unsigned short ushort_t;
typedef unsigned int uint_t;

__device__ __forceinline__ float bits2f(unsigned int u16) {
    union { unsigned int i; float f; } v;
    v.i = (u16 & 0xFFFFu) << 16;
    return v.f;
}

__device__ __forceinline__ ushort_t f2bits(float f) {
    union { float f; unsigned int i; } v;
    v.f = f;
    unsigned int x = v.i;
    if ((x & 0x7F800000u) == 0x7F800000u) return (ushort_t)(x >> 16); // inf/nan
    unsigned int r = (x + 0x7FFFu + ((x >> 16) & 1u)) >> 16;          // RNE
    return (ushort_t)r;
}

// ======================= CSR build (by dst) =======================

__global__ __launch_bounds__(256) void hist_k(const int* __restrict__ ei,
                                              int* __restrict__ deg) {
    int e = blockIdx.x * 256 + threadIdx.x;
    if (e >= N_EDGES) return;
    atomicAdd(&deg[ei[N_EDGES + e]], 1);
}

__global__ __launch_bounds__(256) void scan_a(const int* __restrict__ deg,
                                              int* __restrict__ partial) {
    __shared__ int wsum[4];
    int b = blockIdx.x;
    int i = b * 256 + threadIdx.x;
    int d = (i < N_NODES) ? deg[i] : 0;
#pragma unroll
    for (int off = 32; off >= 1; off >>= 1) d += __shfl_down(d, off, 64);
    if ((threadIdx.x & 63) == 0) wsum[threadIdx.x >> 6] = d;
    __syncthreads();
    if (threadIdx.x == 0)
        partial[b] = wsum[0] + wsum[1] + wsum[2] + wsum[3];
}

__global__ __launch_bounds__(256) void scan_b(int* __restrict__ partial,
                                              int* __restrict__ row) {
    __shared__ int s[256];
    int t = threadIdx.x;
    int v = (t < NCHUNK) ? partial[t] : 0;
    s[t] = v;
    __syncthreads();
#pragma unroll
    for (int off = 1; off < 256; off <<= 1) {
        int a = s[t];
        int u = (t >= off) ? s[t - off] : 0;
        __syncthreads();
        s[t] = a + u;
        __syncthreads();
    }
    if (t < NCHUNK) partial[t] = s[t] - v;   // exclusive
    if (t == 0) row[N_NODES] = N_EDGES;
}

__global__ __launch_bounds__(256) void scan_c(int* __restrict__ deg_cursor,
                                              const int* __restrict__ partial,
                                              int* __restrict__ row) {
    __shared__ int s[256];
    int b = blockIdx.x;
    int t = threadIdx.x;
    int i = b * 256 + t;
    int d = (i < N_NODES) ? deg_cursor[i] : 0;
    s[t] = d;
    __syncthreads();
#pragma unroll
    for (int off = 1; off < 256; off <<= 1) {
        int a = s[t];
        int u = (t >= off) ? s[t - off] : 0;
        __syncthreads();
        s[t] = a + u;
        __syncthreads();
    }
    if (i < N_NODES) {
        int excl = s[t] - d + partial[b];
        row[i] = excl;
        deg_cursor[i] = excl;
    }
}

__global__ __launch_bounds__(256) void fill_k(const int* __restrict__ ei,
                                              int* __restrict__ cursor,
                                              int* __restrict__ bucket) {
    int e = blockIdx.x * 256 + threadIdx.x;
    if (e >= N_EDGES) return;
    int src = ei[e];
    int dst = ei[N_EDGES + e];
    int pos = atomicAdd(&cursor[dst], 1);
    bucket[pos] = src;
}

// ======================= x -> bf16 convert =======================
__global__ __launch_bounds__(256) void cvt_k(const float* __restrict__ x,
                                             uint_t* __restrict__ xu) {
    int i = blockIdx.x * 256 + threadIdx.x;     // over bf16 pairs
    if (i >= N_NODES * IN_CH / 2) return;
    float2 v = ((const float2*)x)[i];
    xu[i] = (uint_t)f2bits(v.x) | ((uint_t)f2bits(v.y) << 16);
}

// ======================= gather aggregations =======================
__global__ __launch_bounds__(256) void gather1(const uint_t* __restrict__ xu,
                                               const int* __restrict__ row,
                                               const int* __restrict__ bucket,
                                               const float* __restrict__ eps1,
                                               float* __restrict__ h) {
    int wid = threadIdx.x >> 6;
    int lane = threadIdx.x & 63;
    int half = lane >> 5;
    int li = lane & 31;
    int n = blockIdx.x * 4 + wid;
    float a0 = 0.0f, a1 = 0.0f;
    if (half == 0) {
        uint_t v = xu[(size_t)n * 32 + li];
        float se = 1.0f + eps1[0];
        a0 = se * bits2f(v);
        a1 = se * bits2f(v >> 16);
    }
    int lo = row[n], hi = row[n + 1];
    for (int i = lo + half; i < hi; i += 2) {
        uint_t u = xu[(size_t)bucket[i] * 32 + li];
        a0 += bits2f(u);
        a1 += bits2f(u >> 16);
    }
    float p0 = __shfl(a0, lane ^ 32);
    float p1 = __shfl(a1, lane ^ 32);
    if (half == 0) {
        float2* outp = (float2*)(h + (size_t)n * IN_CH + 2 * li);
        *outp = make_float2(a0 + p0, a1 + p1);
    }
}

__global__ __launch_bounds__(256) void gather2(const ushort_t* __restrict__ h1,
                                               const int* __restrict__ row,
                                               const int* __restrict__ bucket,
                                               const float* __restrict__ eps2,
                                               float* __restrict__ hbuf) {
    int wid = threadIdx.x >> 6;
    int lane = threadIdx.x & 63;
    int n = blockIdx.x * 4 + wid;
    const uint_t* h1u = (const uint_t*)h1;
    uint_t v = h1u[(size_t)n * 64 + lane];
    float se = 1.0f + eps2[0];
    float a0 = se * bits2f(v), a1 = se * bits2f(v >> 16);
    float b0 = 0.0f, b1 = 0.0f;
    int lo = row[n], hi = row[n + 1];
    int i = lo;
    for (; i + 1 < hi; i += 2) {
        int s0 = bucket[i], s1 = bucket[i + 1];
        uint_t u0 = h1u[(size_t)s0 * 64 + lane];
        uint_t u1 = h1u[(size_t)s1 * 64 + lane];
        a0 += bits2f(u0); a1 += bits2f(u0 >> 16);
        b0 += bits2f(u1); b1 += bits2f(u1 >> 16);
    }
    if (i < hi) {
        uint_t u = h1u[(size_t)bucket[i] * 64 + lane];
        a0 += bits2f(u); a1 += bits2f(u >> 16);
    }
    float2* outp = (float2*)(hbuf + (size_t)n * HIDDEN + 2 * lane);
    *outp = make_float2(a0 + b0, a1 + b1);
}

// ======================= fused MLPs =======================
// 128 threads, NBM=32 nodes/block, per thread 4 cols x 8 nodes micro-tile.
// LDS rows padded +4 floats: row-to-row bank shift 4 -> stage-2 row-group
// reads are <=2-way (free). 16B alignment kept (132*4 = 528 = 33*16).
#define HP (HIDDEN + 4)   // 132
#define IP (IN_CH + 4)    // 68

__device__ __forceinline__ void fma4(float4& acc, const float4& hv,
                                     const float4& w0, const float4& w1,
                                     const float4& w2, const float4& w3) {
    acc.x = fmaf(hv.x, w0.x, acc.x); acc.y = fmaf(hv.x, w0.y, acc.y);
    acc.z = fmaf(hv.x, w0.z, acc.z); acc.w = fmaf(hv.x, w0.w, acc.w);
    acc.x = fmaf(hv.y, w1.x, acc.x); acc.y = fmaf(hv.y, w1.y, acc.y);
    acc.z = fmaf(hv.y, w1.z, acc.z); acc.w = fmaf(hv.y, w1.w, acc.w);
    acc.x = fmaf(hv.z, w2.x, acc.x); acc.y = fmaf(hv.z, w2.y, acc.y);
    acc.z = fmaf(hv.z, w2.z, acc.z); acc.w = fmaf(hv.z, w2.w, acc.w);
    acc.x = fmaf(hv.w, w3.x, acc.x); acc.y = fmaf(hv.w, w3.y, acc.y);
    acc.z = fmaf(hv.w, w3.z, acc.z); acc.w = fmaf(hv.w, w3.w, acc.w);
}

// mlp1: h1 = relu( relu(h@W1+b1) @ W2 + b2 )  -> bf16
__global__ __launch_bounds__(128, 2) void mlp1(const float* __restrict__ h,
                                               const float* __restrict__ W1,
                                               const float* __restrict__ b1,
                                               const float* __restrict__ W2,
                                               const float* __restrict__ b2,
                                               ushort_t* __restrict__ h1) {
    __shared__ float hs[NBM][IP];
    __shared__ float ts[NBM][HP];
    int n0 = blockIdx.x * NBM;
    int t = threadIdx.x;
    // stage h rows (zero-fill tail)
    for (int i = t; i < NBM * (IN_CH / 4); i += 128) {
        int r = i >> 4, c4 = i & 15;
        float4 v = make_float4(0.f, 0.f, 0.f, 0.f);
        if (n0 + r < N_NODES)
            v = *(const float4*)(h + (size_t)(n0 + r) * IN_CH + c4 * 4);
        *(float4*)&hs[r][c4 * 4] = v;
    }
    __syncthreads();
    int j0 = (t & 31) * 4;       // 4 cols
    int q0 = (t >> 5) * 8;       // 8 nodes
    // stage 1: K=64, C=128
    float4 acc[8];
    {
        float4 bv = *(const float4*)&b1[j0];
#pragma unroll
        for (int q = 0; q < 8; q++) acc[q] = bv;
    }
    for (int kb = 0; kb < IN_CH; kb += 4) {
        float4 w0 = *(const float4*)&W1[(size_t)(kb + 0) * HIDDEN + j0];
        float4 w1 = *(const float4*)&W1[(size_t)(kb + 1) * HIDDEN + j0];
        float4 w2 = *(const float4*)&W1[(size_t)(kb + 2) * HIDDEN + j0];
        float4 w3 = *(const float4*)&W1[(size_t)(kb + 3) * HIDDEN + j0];
#pragma unroll
        for (int q = 0; q < 8; q++) {
            float4 hv = *(const float4*)&hs[q0 + q][kb];
            fma4(acc[q], hv, w0, w1, w2, w3);
        }
    }
#pragma unroll
    for (int q = 0; q < 8; q++) {
        float4 r = acc[q];
        r.x = fmaxf(r.x, 0.f); r.y = fmaxf(r.y, 0.f);
        r.z = fmaxf(r.z, 0.f); r.w = fmaxf(r.w, 0.f);
        *(float4*)&ts[q0 + q][j0] = r;
    }
    __syncthreads();
    // stage 2: K=128, C=128
    float4 acc2[8];
    {
        float4 bv = *(const float4*)&b2[j0];
#pragma unroll
        for (int q = 0; q < 8; q++) acc2[q] = bv;
    }
    for (int kb = 0; kb < HIDDEN; kb += 4) {
        float4 w0 = *(const float4*)&W2[(size_t)(kb + 0) * HIDDEN + j0];
        float4 w1 = *(const float4*)&W2[(size_t)(kb + 1) * HIDDEN + j0];
        float4 w2 = *(const float4*)&W2[(size_t)(kb + 2) * HIDDEN + j0];
        float4 w3 = *(const float4*)&W2[(size_t)(kb + 3) * HIDDEN + j0];
#pragma unroll
        for (int q = 0; q < 8; q++) {
            float4 tv = *(const float4*)&ts[q0 + q][kb];
            fma4(acc2[q], tv, w0, w1, w2, w3);
        }
    }
#pragma unroll
    for (int q = 0; q < 8; q++) {
        if (n0 + q0 + q >= N_NODES) break;
        float4 r = acc2[q];
        uint_t lo = (uint_t)f2bits(fmaxf(r.x, 0.f)) | ((uint_t)f2bits(fmaxf(r.y, 0.f)) << 16);
        uint_t hi = (uint_t)f2bits(fmaxf(r.z, 0.f)) | ((uint_t)f2bits(fmaxf(r.w, 0.f)) << 16);
        *(uint2*)&h1[(size_t)(n0 + q0 + q) * HIDDEN + j0] = make_uint2(lo, hi);
    }
}

// mlp2: out = relu(h@W3+b3) @ W4 + b4  -> f32
__global__ __launch_bounds__(128, 2) void mlp2(const float* __restrict__ h,
                                               const float* __restrict__ W3,
                                               const float* __restrict__ b3,
                                               const float* __restrict__ W4,
                                               const float* __restrict__ b4,
                                               float* __restrict__ out) {
    __shared__ float hs[NBM][HP];
    __shared__ float ts[NBM][HP];
    int n0 = blockIdx.x * NBM;
    int t = threadIdx.x;
    for (int i = t; i < NBM * (HIDDEN / 4); i += 128) {
        int r = i >> 5, c4 = i & 31;
        float4 v = make_float4(0.f, 0.f, 0.f, 0.f);
        if (n0 + r < N_NODES)
            v = *(const float4*)(h + (size_t)(n0 + r) * HIDDEN + c4 * 4);
        *(float4*)&hs[r][c4 * 4] = v;
    }
    __syncthreads();
    // stage 1: K=128, C=128; 4 cols x 8 nodes
    int j0 = (t & 31) * 4;
    int q0 = (t >> 5) * 8;
    float4 acc[8];
    {
        float4 bv = *(const float4*)&b3[j0];
#pragma unroll
        for (int q = 0; q < 8; q++) acc[q] = bv;
    }
    for (int kb = 0; kb < HIDDEN; kb += 4) {
        float4 w0 = *(const float4*)&W3[(size_t)(kb + 0) * HIDDEN + j0];
        float4 w1 = *(const float4*)&W3[(size_t)(kb + 1) * HIDDEN + j0];
        float4 w2 = *(const float4*)&W3[(size_t)(kb + 2) * HIDDEN + j0];
        float4 w3 = *(const float4*)&W3[(size_t)(kb + 3) * HIDDEN + j0];
#pragma unroll
        for (int q = 0; q < 8; q++) {
            float4 hv = *(const float4*)&hs[q0 + q][kb];
            fma4(acc[q], hv, w0, w1, w2, w3);
        }
    }
#pragma unroll
    for (int q = 0; q < 8; q++) {
        float4 r = acc[q];
        r.x = fmaxf(r.x, 0.f); r.y = fmaxf(r.y, 0.f);
        r.z = fmaxf(r.z, 0.f); r.w = fmaxf(r.w, 0.f);
        *(float4*)&ts[q0 + q][j0] = r;
    }
    __syncthreads();
    // stage 2: K=128, C=64; 4 cols x 4 nodes
    int j2 = (t & 15) * 4;
    int q2 = (t >> 4) * 4;
    float4 acc2[4];
    {
        float4 bv = *(const float4*)&b4[j2];
#pragma unroll
        for (int q = 0; q < 4; q++) acc2[q] = bv;
    }
    for (int kb = 0; kb < HIDDEN; kb += 4) {
        float4 w0 = *(const float4*)&W4[(size_t)(kb + 0) * OUT_CH + j2];
        float4 w1 = *(const float4*)&W4[(size_t)(kb + 1) * OUT_CH + j2];
        float4 w2 = *(const float4*)&W4[(size_t)(kb + 2) * OUT_CH + j2];
        float4 w3 = *(const float4*)&W4[(size_t)(kb + 3) * OUT_CH + j2];
#pragma unroll
        for (int q = 0; q < 4; q++) {
            float4 tv = *(const float4*)&ts[q2 + q][kb];
            fma4(acc2[q], tv, w0, w1, w2, w3);
        }
    }
#pragma unroll
    for (int q = 0; q < 4; q++) {
        if (n0 + q2 + q >= N_NODES) break;
        *(float4*)&out[(size_t)(n0 + q2 + q) * OUT_CH + j2] = acc2[q];
    }
}

extern "C" void kernel_launch(void* const* d_in, const int* in_sizes, int n_in,
                              void* d_out, int out_size, void* d_ws, size_t ws_size,
                              hipStream_t stream) {
    const float* x    = (const float*)d_in[0];
    const int*   ei   = (const int*)d_in[1];
    const float* W1   = (const float*)d_in[2];
    const float* b1   = (const float*)d_in[3];
    const float* W2   = (const float*)d_in[4];
    const float* b2   = (const float*)d_in[5];
    const float* eps1 = (const float*)d_in[6];
    const float* W3   = (const float*)d_in[7];
    const float* b3   = (const float*)d_in[8];
    const float* W4   = (const float*)d_in[9];
    const float* b4   = (const float*)d_in[10];
    const float* eps2 = (const float*)d_in[11];
    float* out = (float*)d_out;

    float* ws   = (float*)d_ws;
    float* agg1 = ws;
    float* agg2 = ws;
    ushort_t* bufA = (ushort_t*)(ws + (size_t)N_NODES * HIDDEN);
    uint_t* xb     = (uint_t*)bufA;          // used only before mlp1 writes h1
    ushort_t* h1   = bufA;
    int* bucket  = (int*)(ws + (size_t)N_NODES * HIDDEN + (size_t)N_NODES * HIDDEN / 2);
    int* row     = bucket + N_EDGES;
    int* cursor  = row + N_NODES + 4;
    int* partial = cursor + N_NODES;

    // ---- CSR build ----
    hipMemsetAsync(cursor, 0, N_NODES * sizeof(int), stream);
    hist_k<<<(N_EDGES + 255) / 256, 256, 0, stream>>>(ei, cursor);
    scan_a<<<NCHUNK, 256, 0, stream>>>(cursor, partial);
    scan_b<<<1, 256, 0, stream>>>(partial, row);
    scan_c<<<NCHUNK, 256, 0, stream>>>(cursor, partial, row);
    fill_k<<<(N_EDGES + 255) / 256, 256, 0, stream>>>(ei, cursor, bucket);

    // ---- layer 1 ----
    cvt_k<<<(N_NODES * IN_CH / 2 + 255) / 256, 256, 0, stream>>>(x, xb);
    gather1<<<N_NODES / 4, 256, 0, stream>>>(xb, row, bucket, eps1, agg1);
    mlp1<<<(N_NODES + NBM - 1) / NBM, 128, 0, stream>>>(agg1, W1, b1, W2, b2, h1);

    // ---- layer 2 ----
    gather2<<<N_NODES / 4, 256, 0, stream>>>(h1, row, bucket, eps2, agg2);
    mlp2<<<(N_NODES + NBM - 1) / NBM, 128, 0, stream>>>(agg2, W3, b3, W4, b4, out);
}